// Round 1
// baseline (455.793 us; speedup 1.0000x reference)
//
#include <hip/hip_runtime.h>
#include <stdint.h>
#include <math.h>

typedef _Float16 half8_t __attribute__((ext_vector_type(8)));
typedef _Float16 half4_t __attribute__((ext_vector_type(4)));
typedef float floatx4 __attribute__((ext_vector_type(4)));

#define NN 20000
#define NE 40000
#define NG 1000
#define HSTR 136   // fp16 h-row stride: 129 used (k=128 is the b2 virtual row), padded to 17*8

// ---------------- edge MLP layer 1: h = relu(ea @ w1 + b1), stored fp16 ----------------
__global__ __launch_bounds__(256) void h_kernel(
    const float* __restrict__ ea, const float* __restrict__ w1,
    const float* __restrict__ b1, _Float16* __restrict__ h)
{
  int t = threadIdx.x;
  int e = blockIdx.x * 2 + (t >> 7);
  int k = t & 127;
  const float* row = ea + (size_t)e * 5;
  float acc = b1[k];
#pragma unroll
  for (int j = 0; j < 5; ++j) acc = fmaf(row[j], w1[j * 128 + k], acc);
  acc = fmaxf(acc, 0.f);
  h[(size_t)e * HSTR + k] = (_Float16)acc;
  if (k == 0) h[(size_t)e * HSTR + 128] = (_Float16)1.0f;
}

// ---- w2 (+b2 as last K rows) -> fp16, pre-swizzled into per-chunk B-fragment images ----
// flat idx = ((c*CT + ct)*64 + lane); element j of that 8-vec holds W[32c+8*(lane>>4)+j][16ct+(lane&15)]
__global__ __launch_bounds__(256) void prep_w2h(
    const float* __restrict__ w2, const float* __restrict__ b2,
    _Float16* __restrict__ w2h, int mi, int mo, int NC)
{
  int CT = mo >> 4;
  int total = NC * CT * 64;
  int idx = blockIdx.x * 256 + threadIdx.x;
  if (idx >= total) return;
  int l = idx & 63;
  int ct = (idx >> 6) % CT;
  int c = idx / (64 * CT);
  int q = l >> 4;
  int n = ct * 16 + (l & 15);
  int K1 = 128 * mi, K2 = 129 * mi;
  half8_t v;
#pragma unroll
  for (int j = 0; j < 8; ++j) {
    int r = c * 32 + q * 8 + j;
    float f = 0.f;
    if (r < K1) f = w2[(size_t)r * mo + n];
    else if (r < K2) f = b2[(size_t)(r - K1) * mo + n];
    v[j] = (_Float16)f;
  }
  *(half8_t*)(w2h + (size_t)idx * 8) = v;
}

// ---------------- x_next = x @ root + bias ----------------
__global__ __launch_bounds__(256) void root_kernel(
    const float* __restrict__ x, const float* __restrict__ root,
    const float* __restrict__ bias, float* __restrict__ xn,
    int mi, int mo, int xstride)
{
  int t = threadIdx.x;
  int o = t & (mo - 1);
  int ln = t / mo;
  int npb = 256 / mo;
  int n = blockIdx.x * npb + ln;
  if (n >= NN) return;
  const float* xr = x + (size_t)n * xstride;
  float acc = bias[o];
  for (int i = 0; i < mi; ++i) acc = fmaf(xr[i], root[i * mo + o], acc);
  xn[(size_t)n * mo + o] = acc;
}

// ---------------- fused message GEMM + scatter-add ----------------
// C[E,mo] = G[E,129*mi] @ W ; G[e][k*mi+i] = h[e][k]*x[src[e]][i], h[e][128]=1 handles b2.
template <int MI, int MO>
__global__ __launch_bounds__(256) void msg_kernel(
    const _Float16* __restrict__ h, const float* __restrict__ x,
    const int* __restrict__ src, const int* __restrict__ dst,
    const _Float16* __restrict__ w2h, float* __restrict__ xn)
{
  constexpr int MP = (MI == 13) ? 24 : (MI + 8);   // xss padded stride (bank spread, keeps 16B align)
  constexpr int KEXT = 129 * MI;
  constexpr int NC = (KEXT + 31) / 32;
  constexpr int CHB = 64 * MO;                     // bytes per W chunk image (32*MO fp16)
  constexpr int ASUB = (MO == 64) ? 2 : 1;

  __shared__ _Float16 hs[64 * HSTR];
  __shared__ _Float16 xss[64 * MP];
  __shared__ _Float16 wsb[32 * MO];
  __shared__ int dsts[64];

  const int t = threadIdx.x;
  const int wave = t >> 6, lane = t & 63;
  const int l15 = lane & 15, q = lane >> 4;
  const int e0 = blockIdx.x * 64;

  // ---- stage h rows (fp16 raw copy), gathered x rows (fp32->fp16), dst indices ----
  {
    int row = t >> 2;
    const uint4* gs = (const uint4*)(h + (size_t)(e0 + row) * HSTR);
    uint4* ld = (uint4*)(hs + row * HSTR);
    for (int s = (t & 3); s < HSTR / 8; s += 4) ld[s] = gs[s];
    int se = src[e0 + row];
    if constexpr (MI % 4 == 0) {
      const float* xr = x + (size_t)se * MI;
      for (int i0 = (t & 3) * 4; i0 < MI; i0 += 16) {
        floatx4 v = *(const floatx4*)(xr + i0);
        half4_t hv = { (_Float16)v[0], (_Float16)v[1], (_Float16)v[2], (_Float16)v[3] };
        *(half4_t*)(xss + row * MP + i0) = hv;
      }
    } else {
      for (int i = (t & 3); i < MI; i += 4)
        xss[row * MP + i] = (_Float16)x[(size_t)se * MI + i];
    }
    if (t < 64) dsts[t] = dst[e0 + t];
  }

  int ebase, cbase;
  if constexpr (MO == 64) { ebase = (wave & 1) * 32; cbase = (wave >> 1) * 32; }
  else                    { ebase = wave * 16;       cbase = 0; }

  floatx4 acc[ASUB][2];
#pragma unroll
  for (int s = 0; s < ASUB; ++s)
#pragma unroll
    for (int b = 0; b < 2; ++b) acc[s][b] = (floatx4){0.f, 0.f, 0.f, 0.f};

  const char* wg = (const char*)w2h;
  uint4 wr4; uint2 wr2;
  if constexpr (MO == 64) wr4 = *(const uint4*)(wg + t * 16);
  else                    wr2 = *(const uint2*)(wg + t * 8);

  __syncthreads();

  for (int c = 0; c < NC; ++c) {
    // deposit prefetched W chunk into LDS
    if constexpr (MO == 64) *(uint4*)((char*)wsb + t * 16) = wr4;
    else                    *(uint2*)((char*)wsb + t * 8)  = wr2;
    __syncthreads();
    // prefetch next chunk (latency hidden under MFMAs below)
    if (c + 1 < NC) {
      if constexpr (MO == 64) wr4 = *(const uint4*)(wg + (size_t)(c + 1) * CHB + t * 16);
      else                    wr2 = *(const uint2*)(wg + (size_t)(c + 1) * CHB + t * 8);
    }

    // ---- generate A fragments: lane holds A[m=l15][k=8q+j] ----
    half8_t afr[ASUB];
    if constexpr (MI == 64) {
      int k = c >> 1, i0 = ((c & 1) << 5) + q * 8;
#pragma unroll
      for (int s = 0; s < ASUB; ++s) {
        int e = ebase + s * 16 + l15;
        _Float16 hv = hs[e * HSTR + k];
        half8_t xv = *(const half8_t*)(xss + e * MP + i0);
        afr[s] = xv * hv;
      }
    } else if constexpr (MI == 32) {
      int i0 = q * 8;
#pragma unroll
      for (int s = 0; s < ASUB; ++s) {
        int e = ebase + s * 16 + l15;
        _Float16 hv = hs[e * HSTR + c];
        half8_t xv = *(const half8_t*)(xss + e * MP + i0);
        afr[s] = xv * hv;
      }
    } else {  // MI == 13 generic (padded K region multiplies zeroed W rows)
#pragma unroll
      for (int s = 0; s < ASUB; ++s) {
        int e = ebase + s * 16 + l15;
        half8_t av;
#pragma unroll
        for (int j = 0; j < 8; ++j) {
          int kk = c * 32 + q * 8 + j;
          int k = kk / MI, i = kk - k * MI;
          av[j] = hs[e * HSTR + k] * xss[e * MP + i];
        }
        afr[s] = av;
      }
    }

#pragma unroll
    for (int b = 0; b < 2; ++b) {
      int ct = (cbase >> 4) + b;
      half8_t bfr = *(const half8_t*)(wsb + (ct * 64 + lane) * 8);
#pragma unroll
      for (int s = 0; s < ASUB; ++s)
        acc[s][b] = __builtin_amdgcn_mfma_f32_16x16x32_f16(afr[s], bfr, acc[s][b], 0, 0, 0);
    }
    __syncthreads();
  }

  // ---- epilogue: D row = 4q+r, col = l15; scatter-add to x_next[dst] ----
#pragma unroll
  for (int s = 0; s < ASUB; ++s) {
    int el = ebase + s * 16 + q * 4;
#pragma unroll
    for (int b = 0; b < 2; ++b) {
      int n = cbase + b * 16 + l15;
#pragma unroll
      for (int r = 0; r < 4; ++r)
        atomicAdd(&xn[(size_t)dsts[el + r] * MO + n], acc[s][b][r]);
    }
  }
}

// ---------------- misc ----------------
__global__ __launch_bounds__(256) void zero_kernel(float* p, int n) {
  int i = blockIdx.x * 256 + threadIdx.x;
  if (i < n) p[i] = 0.f;
}

__global__ __launch_bounds__(256) void elu_kernel(float* __restrict__ p, int n) {
  int i = blockIdx.x * 256 + threadIdx.x;
  if (i < n) { float v = p[i]; p[i] = v > 0.f ? v : (expf(v) - 1.f); }
}

__global__ __launch_bounds__(256) void pool_kernel(
    const float* __restrict__ x, const int* __restrict__ batch,
    float* __restrict__ sums, float* __restrict__ cnt)
{
  int idx = blockIdx.x * 256 + threadIdx.x;
  if (idx >= NN * 64) return;
  int n = idx >> 6, o = idx & 63;
  int g = batch[n];
  atomicAdd(&sums[(size_t)g * 64 + o], x[idx]);
  if (o == 0) atomicAdd(&cnt[g], 1.f);
}

__global__ __launch_bounds__(64) void fc_kernel(
    const float* __restrict__ sums, const float* __restrict__ cnt,
    const float* __restrict__ f1w, const float* __restrict__ f1b,
    const float* __restrict__ f2w, const float* __restrict__ f2b,
    const float* __restrict__ f3w, const float* __restrict__ f3b,
    float* __restrict__ out)
{
  __shared__ float xg[64]; __shared__ float a1[32]; __shared__ float a2[16];
  int g = blockIdx.x, t = threadIdx.x;
  float c = fmaxf(cnt[g], 1.f);
  xg[t] = sums[(size_t)g * 64 + t] / c;
  __syncthreads();
  if (t < 32) {
    float acc = f1b[t];
    for (int i = 0; i < 64; ++i) acc = fmaf(xg[i], f1w[i * 32 + t], acc);
    a1[t] = acc > 0.f ? acc : (expf(acc) - 1.f);
  }
  __syncthreads();
  if (t < 16) {
    float acc = f2b[t];
    for (int i = 0; i < 32; ++i) acc = fmaf(a1[i], f2w[i * 16 + t], acc);
    a2[t] = acc > 0.f ? acc : (expf(acc) - 1.f);
  }
  __syncthreads();
  if (t == 0) {
    float acc = f3b[0];
    for (int i = 0; i < 16; ++i) acc = fmaf(a2[i], f3w[i], acc);
    out[g] = acc;
  }
}

extern "C" void kernel_launch(void* const* d_in, const int* in_sizes, int n_in,
                              void* d_out, int out_size, void* d_ws, size_t ws_size,
                              hipStream_t stream)
{
  const float* x_in  = (const float*)d_in[0];
  const int*   ei    = (const int*)d_in[1];
  const float* ea    = (const float*)d_in[2];
  const int*   batch = (const int*)d_in[3];
  const float* W1[3] = {(const float*)d_in[4],  (const float*)d_in[10], (const float*)d_in[16]};
  const float* B1[3] = {(const float*)d_in[5],  (const float*)d_in[11], (const float*)d_in[17]};
  const float* W2[3] = {(const float*)d_in[6],  (const float*)d_in[12], (const float*)d_in[18]};
  const float* B2[3] = {(const float*)d_in[7],  (const float*)d_in[13], (const float*)d_in[19]};
  const float* RT[3] = {(const float*)d_in[8],  (const float*)d_in[14], (const float*)d_in[20]};
  const float* BS[3] = {(const float*)d_in[9],  (const float*)d_in[15], (const float*)d_in[21]};
  const float* f1w = (const float*)d_in[22]; const float* f1b = (const float*)d_in[23];
  const float* f2w = (const float*)d_in[24]; const float* f2b = (const float*)d_in[25];
  const float* f3w = (const float*)d_in[26]; const float* f3b = (const float*)d_in[27];

  char* ws = (char*)d_ws;
  size_t off = 0;
  auto alloc = [&](size_t bytes) { void* p = ws + off; off += (bytes + 255) & ~(size_t)255; return p; };
  float*    xA   = (float*)alloc((size_t)NN * 64 * 4);
  float*    xB   = (float*)alloc((size_t)NN * 64 * 4);
  _Float16* hbuf = (_Float16*)alloc((size_t)NE * HSTR * 2);
  _Float16* w2h  = (_Float16*)alloc((size_t)258 * 4096);
  float*    sums = (float*)alloc((size_t)NG * 65 * 4);
  float*    cnt  = sums + (size_t)NG * 64;

  const int* srcp = ei;
  const int* dstp = ei + NE;

  const int MIs[3] = {13, 32, 64};
  const int MOs[3] = {32, 64, 64};
  const float* xin_l[3]  = {x_in, xA, xB};
  float*       xout_l[3] = {xA, xB, xA};

  for (int l = 0; l < 3; ++l) {
    int mi = MIs[l], mo = MOs[l];
    int NC = (129 * mi + 31) / 32;
    int CT = mo >> 4;
    h_kernel<<<NE / 2, 256, 0, stream>>>(ea, W1[l], B1[l], hbuf);
    prep_w2h<<<(NC * CT * 64 + 255) / 256, 256, 0, stream>>>(W2[l], B2[l], w2h, mi, mo, NC);
    root_kernel<<<NN / (256 / mo), 256, 0, stream>>>(xin_l[l], RT[l], BS[l], xout_l[l], mi, mo, mi);
    if (l == 0)
      msg_kernel<13, 32><<<NE / 64, 256, 0, stream>>>(hbuf, xin_l[l], srcp, dstp, w2h, xout_l[l]);
    else if (l == 1)
      msg_kernel<32, 64><<<NE / 64, 256, 0, stream>>>(hbuf, xin_l[l], srcp, dstp, w2h, xout_l[l]);
    else
      msg_kernel<64, 64><<<NE / 64, 256, 0, stream>>>(hbuf, xin_l[l], srcp, dstp, w2h, xout_l[l]);
    elu_kernel<<<(NN * mo + 255) / 256, 256, 0, stream>>>(xout_l[l], NN * mo);
  }

  zero_kernel<<<(NG * 65 + 255) / 256, 256, 0, stream>>>(sums, NG * 65);
  pool_kernel<<<(NN * 64 + 255) / 256, 256, 0, stream>>>(xA, batch, sums, cnt);
  fc_kernel<<<NG, 64, 0, stream>>>(sums, cnt, f1w, f1b, f2w, f2b, f3w, f3b, (float*)d_out);
}

// Round 2
// 399.080 us; speedup vs baseline: 1.1421x; 1.1421x over previous
//
#include <hip/hip_runtime.h>
#include <stdint.h>
#include <math.h>

typedef _Float16 half8_t __attribute__((ext_vector_type(8)));
typedef float floatx4 __attribute__((ext_vector_type(4)));

#define NN 20000
#define NE 40000
#define NG 1000
#define NSPLIT 2

// ---------------- x0 -> fp16 padded [N,16] ----------------
__global__ __launch_bounds__(256) void x0cvt_kernel(
    const float* __restrict__ x, _Float16* __restrict__ xe16)
{
  int idx = blockIdx.x * 256 + threadIdx.x;
  if (idx >= NN * 16) return;
  int n = idx >> 4, i = idx & 15;
  xe16[idx] = (i < 13) ? (_Float16)x[n * 13 + i] : (_Float16)0.f;
}

// ---------------- elu + cvt: xn -> elu'd fp32 + fp16 ----------------
__global__ __launch_bounds__(256) void elu_cvt_kernel(
    const float* __restrict__ xn, float* __restrict__ e32,
    _Float16* __restrict__ e16, int n)
{
  int i = blockIdx.x * 256 + threadIdx.x;
  if (i >= n) return;
  float v = xn[i];
  v = v > 0.f ? v : (expf(v) - 1.f);
  e32[i] = v;
  e16[i] = (_Float16)v;
}

// ---- w2 (+b2 virtual row, K padded to mi_pad) -> fp16 per-chunk B-fragment images ----
// flat idx = ((c*CT + ct)*64 + lane); elem j: W[32c+8q+j] with k=r>>mpsh, i=r&(mip-1)
__global__ __launch_bounds__(256) void prep_w2h(
    const float* __restrict__ w2, const float* __restrict__ b2,
    _Float16* __restrict__ w2h, int mi, int mo, int mpsh, int NC)
{
  int CT = mo >> 4;
  int total = NC * CT * 64;
  int idx = blockIdx.x * 256 + threadIdx.x;
  if (idx >= total) return;
  int l = idx & 63;
  int ct = (idx >> 6) % CT;
  int c = idx / (64 * CT);
  int q = l >> 4;
  int n = ct * 16 + (l & 15);
  int mask = (1 << mpsh) - 1;
  half8_t v;
#pragma unroll
  for (int j = 0; j < 8; ++j) {
    int r = c * 32 + q * 8 + j;
    int k = r >> mpsh, i = r & mask;
    float f = 0.f;
    if (i < mi) {
      if (k < 128) f = w2[(size_t)(k * mi + i) * mo + n];
      else if (k == 128) f = b2[(size_t)i * mo + n];
    }
    v[j] = (_Float16)f;
  }
  *(half8_t*)(w2h + (size_t)idx * 8) = v;
}

// ---------------- x_next = x @ root + bias (init for scatter) ----------------
__global__ __launch_bounds__(256) void root_kernel(
    const float* __restrict__ x, const float* __restrict__ root,
    const float* __restrict__ bias, float* __restrict__ xn,
    int mi, int mo)
{
  int t = threadIdx.x;
  int o = t & (mo - 1);
  int ln = t / mo;
  int npb = 256 / mo;
  int n = blockIdx.x * npb + ln;
  if (n >= NN) return;
  const float* xr = x + (size_t)n * mi;
  float acc = bias[o];
  for (int i = 0; i < mi; ++i) acc = fmaf(xr[i], root[i * mo + o], acc);
  xn[(size_t)n * mo + o] = acc;
}

// ---------------- fused h-MLP + message GEMM + scatter-add ----------------
// C[E,mo] = G[E,129*MIP] @ W ; G[e][k*MIP+i] = h[e][k]*x[e][i] (fp16), h[.][128]=1.
// Block: 256 edges, 4 waves as 2(M=128) x 2(N=MO/2); x frags in regs; split-K=2.
template <int MIP, int MO, int NC>
__global__ __launch_bounds__(256, 2) void msg2_kernel(
    const float* __restrict__ ea, const float* __restrict__ w1,
    const float* __restrict__ b1, const _Float16* __restrict__ xe,
    const int* __restrict__ src, const int* __restrict__ dst,
    const _Float16* __restrict__ w2h, float* __restrict__ xn)
{
  constexpr int CT = MO / 16;
  constexpr int NCT = CT / 2;          // ct tiles per wave
  constexpr int HST = 66;              // 33 words stride: conflict-free scalar reads
  constexpr int XLSS = MIP + 8;        // 16B-aligned rows, once-per-block reads
  constexpr int CHB = 32 * MO * 2;     // W chunk bytes (MO64: 4096, MO32: 2048)
  constexpr int PFB = CHB / 256;       // per-thread deposit bytes (16 or 8)
  constexpr int XV = (MIP == 64) ? 2 : 1;

  __shared__ _Float16 hs[256 * HST];
  __shared__ _Float16 xls[256 * XLSS];
  __shared__ uint4 wsb[2][CHB / 16];
  __shared__ int dsts[256];

  const int t = threadIdx.x;
  const int wave = t >> 6, lane = t & 63;
  const int l15 = lane & 15, q = lane >> 4;
  const int split = blockIdx.x & (NSPLIT - 1);
  const int eblk = blockIdx.x >> 1;
  const int e0 = eblk * 256;

  const int c0 = (NC * split) / NSPLIT;
  const int c1 = (NC * (split + 1)) / NSPLIT;
  int kg0, kcnt;
  if constexpr (MIP == 64) { kg0 = c0 >> 1; kcnt = ((c1 - 1) >> 1) - kg0 + 1; }
  else if constexpr (MIP == 32) { kg0 = c0; kcnt = c1 - c0; }
  else { kg0 = 2 * c0; kcnt = 2 * (c1 - c0); }

  // ---- stage: edge attrs to regs, dst, x rows -> xls, h -> hs ----
  int eg = e0 + t; if (eg >= NE) eg = NE - 1;
  dsts[t] = dst[eg];
  float ear[5];
#pragma unroll
  for (int j = 0; j < 5; ++j) ear[j] = ea[(size_t)eg * 5 + j];
  {
    const uint4* xr = (const uint4*)(xe + (size_t)src[eg] * MIP);
    uint4* xd = (uint4*)(xls + t * XLSS);
#pragma unroll
    for (int u = 0; u < MIP / 8; ++u) xd[u] = xr[u];
  }
  for (int kl = 0; kl < kcnt; ++kl) {
    int kg = kg0 + kl;
    float v;
    if (kg < 128) {
      v = b1[kg];
#pragma unroll
      for (int j = 0; j < 5; ++j) v = fmaf(ear[j], w1[j * 128 + kg], v);
      v = fmaxf(v, 0.f);
    } else v = (kg == 128) ? 1.f : 0.f;
    hs[t * HST + kl] = (_Float16)v;
  }
  __syncthreads();

  const int mbase = (wave & 1) * 128;
  const int ctbase = (wave >> 1) * NCT;

  // ---- x fragments to registers (read LDS once) ----
  half8_t xf[8][XV];
#pragma unroll
  for (int s = 0; s < 8; ++s) {
    int el = mbase + s * 16 + l15;
    int i0 = (MIP == 16) ? (q & 1) * 8 : q * 8;
    xf[s][0] = *(const half8_t*)(xls + el * XLSS + i0);
    if constexpr (MIP == 64)
      xf[s][XV - 1] = *(const half8_t*)(xls + el * XLSS + 32 + q * 8);
  }

  floatx4 acc[8][NCT];
#pragma unroll
  for (int s = 0; s < 8; ++s)
#pragma unroll
    for (int b = 0; b < NCT; ++b) acc[s][b] = (floatx4){0.f, 0.f, 0.f, 0.f};

  // W prefetch chunk c0
  uint4 w4; uint2 w2r;
  if constexpr (PFB == 16) w4 = *(const uint4*)((const char*)w2h + (size_t)c0 * CHB + t * 16);
  else w2r = *(const uint2*)((const char*)w2h + (size_t)c0 * CHB + t * 8);

  auto body = [&](int c, int xsel) {
    const _Float16* wb = (const _Float16*)wsb[(c - c0) & 1];
    half8_t bf[NCT];
#pragma unroll
    for (int b = 0; b < NCT; ++b)
      bf[b] = *(const half8_t*)(wb + ((ctbase + b) * 64 + lane) * 8);
#pragma unroll
    for (int s = 0; s < 8; ++s) {
      int el = mbase + s * 16 + l15;
      int kl;
      if constexpr (MIP == 64) kl = (c >> 1) - kg0;
      else if constexpr (MIP == 32) kl = c - c0;
      else kl = 2 * (c - c0) + (q >> 1);
      _Float16 hv = hs[el * HST + kl];
      half8_t af = xf[s][xsel ? (XV - 1) : 0] * hv;
#pragma unroll
      for (int b = 0; b < NCT; ++b)
        acc[s][b] = __builtin_amdgcn_mfma_f32_16x16x32_f16(af, bf[b], acc[s][b], 0, 0, 0);
    }
  };

  for (int c = c0; c < c1; ++c) {
    // deposit prefetched W chunk (double-buffered: one barrier per chunk)
    if constexpr (PFB == 16) wsb[(c - c0) & 1][t] = w4;
    else ((uint2*)wsb[(c - c0) & 1])[t] = w2r;
    __syncthreads();
    if (c + 1 < c1) {
      if constexpr (PFB == 16) w4 = *(const uint4*)((const char*)w2h + (size_t)(c + 1) * CHB + t * 16);
      else w2r = *(const uint2*)((const char*)w2h + (size_t)(c + 1) * CHB + t * 8);
    }
    if constexpr (MIP == 64) { if (c & 1) body(c, 1); else body(c, 0); }
    else body(c, 0);
  }

  // ---- epilogue: D row=4q+r, col=l15; scatter-add ----
#pragma unroll
  for (int s = 0; s < 8; ++s) {
    int rowb = mbase + s * 16 + q * 4;
#pragma unroll
    for (int b = 0; b < NCT; ++b) {
      int n = (ctbase + b) * 16 + l15;
#pragma unroll
      for (int r = 0; r < 4; ++r) {
        int row = rowb + r;
        if (e0 + row < NE)
          atomicAdd(&xn[(size_t)dsts[row] * MO + n], acc[s][b][r]);
      }
    }
  }
}

// ---------------- tail ----------------
__global__ __launch_bounds__(256) void zero_kernel(float* p, int n) {
  int i = blockIdx.x * 256 + threadIdx.x;
  if (i < n) p[i] = 0.f;
}

__global__ __launch_bounds__(256) void pool_kernel(
    const float* __restrict__ x, const int* __restrict__ batch,
    float* __restrict__ sums, float* __restrict__ cnt)
{
  int idx = blockIdx.x * 256 + threadIdx.x;
  if (idx >= NN * 64) return;
  int n = idx >> 6, o = idx & 63;
  int g = batch[n];
  float v = x[idx];
  v = v > 0.f ? v : (expf(v) - 1.f);   // fused ELU of layer-2 output
  atomicAdd(&sums[(size_t)g * 64 + o], v);
  if (o == 0) atomicAdd(&cnt[g], 1.f);
}

__global__ __launch_bounds__(64) void fc_kernel(
    const float* __restrict__ sums, const float* __restrict__ cnt,
    const float* __restrict__ f1w, const float* __restrict__ f1b,
    const float* __restrict__ f2w, const float* __restrict__ f2b,
    const float* __restrict__ f3w, const float* __restrict__ f3b,
    float* __restrict__ out)
{
  __shared__ float xg[64]; __shared__ float a1[32]; __shared__ float a2[16];
  int g = blockIdx.x, t = threadIdx.x;
  float c = fmaxf(cnt[g], 1.f);
  xg[t] = sums[(size_t)g * 64 + t] / c;
  __syncthreads();
  if (t < 32) {
    float acc = f1b[t];
    for (int i = 0; i < 64; ++i) acc = fmaf(xg[i], f1w[i * 32 + t], acc);
    a1[t] = acc > 0.f ? acc : (expf(acc) - 1.f);
  }
  __syncthreads();
  if (t < 16) {
    float acc = f2b[t];
    for (int i = 0; i < 32; ++i) acc = fmaf(a1[i], f2w[i * 16 + t], acc);
    a2[t] = acc > 0.f ? acc : (expf(acc) - 1.f);
  }
  __syncthreads();
  if (t == 0) {
    float acc = f3b[0];
    for (int i = 0; i < 16; ++i) acc = fmaf(a2[i], f3w[i], acc);
    out[g] = acc;
  }
}

extern "C" void kernel_launch(void* const* d_in, const int* in_sizes, int n_in,
                              void* d_out, int out_size, void* d_ws, size_t ws_size,
                              hipStream_t stream)
{
  const float* x_in  = (const float*)d_in[0];
  const int*   ei    = (const int*)d_in[1];
  const float* ea    = (const float*)d_in[2];
  const int*   batch = (const int*)d_in[3];
  const float* W1[3] = {(const float*)d_in[4],  (const float*)d_in[10], (const float*)d_in[16]};
  const float* B1[3] = {(const float*)d_in[5],  (const float*)d_in[11], (const float*)d_in[17]};
  const float* W2[3] = {(const float*)d_in[6],  (const float*)d_in[12], (const float*)d_in[18]};
  const float* B2[3] = {(const float*)d_in[7],  (const float*)d_in[13], (const float*)d_in[19]};
  const float* RT[3] = {(const float*)d_in[8],  (const float*)d_in[14], (const float*)d_in[20]};
  const float* BS[3] = {(const float*)d_in[9],  (const float*)d_in[15], (const float*)d_in[21]};
  const float* f1w = (const float*)d_in[22]; const float* f1b = (const float*)d_in[23];
  const float* f2w = (const float*)d_in[24]; const float* f2b = (const float*)d_in[25];
  const float* f3w = (const float*)d_in[26]; const float* f3b = (const float*)d_in[27];

  char* ws = (char*)d_ws;
  size_t off = 0;
  auto alloc = [&](size_t bytes) { void* p = ws + off; off += (bytes + 255) & ~(size_t)255; return p; };
  float*    xn1   = (float*)alloc((size_t)NN * 64 * 4);
  float*    xn2   = (float*)alloc((size_t)NN * 64 * 4);   // xn0 aliases front
  _Float16* e16_1 = (_Float16*)alloc((size_t)NN * 32 * 2);
  _Float16* e16_2 = (_Float16*)alloc((size_t)NN * 64 * 2); // e16_0 aliases front
  float*    e32_2 = (float*)alloc((size_t)NN * 64 * 4);    // e32_1 aliases front
  _Float16* w2h   = (_Float16*)alloc((size_t)258 * 4 * 64 * 8 * 2);
  float*    sums  = (float*)alloc((size_t)NG * 65 * 4);
  float*    cnt   = sums + (size_t)NG * 64;

  float*    xn0   = xn2;     // dead before xn2 is written
  _Float16* e16_0 = e16_2;   // dead before e16_2 is written
  float*    e32_1 = e32_2;   // dead before e32_2 is written

  const int* srcp = ei;
  const int* dstp = ei + NE;
  const int NBLK = (NE + 255) / 256;   // 157

  // ---- layer 0: MI 13(pad16) -> MO 32 ----
  prep_w2h<<<(65 * 2 * 64 + 255) / 256, 256, 0, stream>>>(W2[0], B2[0], w2h, 13, 32, 4, 65);
  x0cvt_kernel<<<(NN * 16 + 255) / 256, 256, 0, stream>>>(x_in, e16_0);
  root_kernel<<<NN / 8, 256, 0, stream>>>(x_in, RT[0], BS[0], xn0, 13, 32);
  msg2_kernel<16, 32, 65><<<NBLK * NSPLIT, 256, 0, stream>>>(
      ea, W1[0], B1[0], e16_0, srcp, dstp, w2h, xn0);
  elu_cvt_kernel<<<(NN * 32 + 255) / 256, 256, 0, stream>>>(xn0, e32_1, e16_1, NN * 32);

  // ---- layer 1: MI 32 -> MO 64 ----
  prep_w2h<<<(129 * 4 * 64 + 255) / 256, 256, 0, stream>>>(W2[1], B2[1], w2h, 32, 64, 5, 129);
  root_kernel<<<NN / 4, 256, 0, stream>>>(e32_1, RT[1], BS[1], xn1, 32, 64);
  msg2_kernel<32, 64, 129><<<NBLK * NSPLIT, 256, 0, stream>>>(
      ea, W1[1], B1[1], e16_1, srcp, dstp, w2h, xn1);
  elu_cvt_kernel<<<(NN * 64 + 255) / 256, 256, 0, stream>>>(xn1, e32_2, e16_2, NN * 64);

  // ---- layer 2: MI 64 -> MO 64 ----
  prep_w2h<<<(258 * 4 * 64 + 255) / 256, 256, 0, stream>>>(W2[2], B2[2], w2h, 64, 64, 6, 258);
  root_kernel<<<NN / 4, 256, 0, stream>>>(e32_2, RT[2], BS[2], xn2, 64, 64);
  msg2_kernel<64, 64, 258><<<NBLK * NSPLIT, 256, 0, stream>>>(
      ea, W1[2], B1[2], e16_2, srcp, dstp, w2h, xn2);

  // ---- pooling (fused ELU) + FC head ----
  zero_kernel<<<(NG * 65 + 255) / 256, 256, 0, stream>>>(sums, NG * 65);
  pool_kernel<<<(NN * 64 + 255) / 256, 256, 0, stream>>>(xn2, batch, sums, cnt);
  fc_kernel<<<NG, 64, 0, stream>>>(sums, cnt, f1w, f1b, f2w, f2b, f3w, f3b, (float*)d_out);
}